// Round 5
// baseline (131.231 us; speedup 1.0000x reference)
//
#include <hip/hip_runtime.h>
#include <stdint.h>

// Problem constants (fixed by the reference)
#define BATCH   4096
#define IN_DIM  1024
#define OUT_DIM 1024

typedef __bf16 bf16x8 __attribute__((ext_vector_type(8)));
typedef float  f32x4  __attribute__((ext_vector_type(4)));
typedef unsigned short u16x8 __attribute__((ext_vector_type(8)));

// fp32 -> bf16 bits, round-to-nearest-even
__device__ __forceinline__ uint16_t f2bf(float f) {
    union { float f; uint32_t u; } v; v.f = f;
    uint32_t u = v.u;
    uint32_t r = (u + 0x7FFFu + ((u >> 16) & 1u)) >> 16;
    return (uint16_t)r;
}

__device__ __forceinline__ float bf2f(uint16_t h) {
    union { uint32_t u; float f; } v; v.u = ((uint32_t)h) << 16;
    return v.f;
}

// ---------------------------------------------------------------------------
// prep: blocks 0..4095   -> convert x row b to bf16, compute alpha[b][0..3]
//       blocks 4096..8191 -> convert W (flat 4M floats) to bf16
// ---------------------------------------------------------------------------
__global__ __launch_bounds__(256) void prep(
    const float* __restrict__ x, const float* __restrict__ phase,
    const float* __restrict__ basis, const float* __restrict__ W,
    uint16_t* __restrict__ xb, uint16_t* __restrict__ Wb,
    float* __restrict__ alphaWS)
{
    const int bid = blockIdx.x;
    const int tid = threadIdx.x;

    if (bid < BATCH) {
        const int b = bid;
        const float HALF_PI = 1.5707963267948966f;
        float s  = phase[b] / HALF_PI;
        int   q  = (int)floorf(s);
        q = q < 0 ? 0 : (q > 3 ? 3 : q);
        float t  = s - (float)q;
        float t2 = t * t, t3 = t2 * t;

        float coef[4];
#pragma unroll
        for (int j = 0; j < 4; ++j)
            coef[j] = t3 * basis[j] + t2 * basis[4 + j] + t * basis[8 + j] + basis[12 + j];

        // CPI[q][k] = (q+k+3)%4  =>  alpha[c] = coef[(c - q + 1) & 3]
        if (tid < 4) alphaWS[b * 4 + tid] = coef[(tid - q + 1) & 3];

        float4 xv = ((const float4*)(x + (size_t)b * IN_DIM))[tid];
        ushort4 o;
        o.x = f2bf(xv.x); o.y = f2bf(xv.y); o.z = f2bf(xv.z); o.w = f2bf(xv.w);
        ((ushort4*)(xb + (size_t)b * IN_DIM))[tid] = o;
    } else {
        const int j = bid - BATCH;                 // 0..4095, W has 1M float4s
        float4 wv = ((const float4*)W)[j * 256 + tid];
        ushort4 o;
        o.x = f2bf(wv.x); o.y = f2bf(wv.y); o.z = f2bf(wv.z); o.w = f2bf(wv.w);
        ((ushort4*)Wb)[j * 256 + tid] = o;
    }
}

// ---------------------------------------------------------------------------
// gemm_split: P_c[m,n] = bf16( bias[c,n] + sum_k x[m,k] * W[c,n,k] )
// 128x128 tile, BK=64, 256 threads (2x2 waves, each 64x64 via 4x4 MFMA).
// grid = (32 M-tiles, 8 N-tiles, 4 c) = 1024 blocks -> 4 blocks/CU.
// K-loop: global_load_lds width=16 + XOR chunk swizzle (0 bank conflicts, R2+).
// Epilogue: acc(+bias) -> LDS (bank-swizzled scatter) -> contiguous b128
// re-read -> fully-coalesced dwordx4 stores of bf16 P (replaces 64 scalar
// 2-byte global stores per lane).
// ---------------------------------------------------------------------------
__global__ __launch_bounds__(256, 4) void gemm_split(
    const uint16_t* __restrict__ xb, const uint16_t* __restrict__ Wb,
    const float* __restrict__ biases, uint16_t* __restrict__ P)
{
    __shared__ uint16_t smem[2 * 128 * 64];   // As | Bs, reused by epilogue
    uint16_t* As = smem;
    uint16_t* Bs = smem + 128 * 64;

    const int tid  = threadIdx.x;
    const int lane = tid & 63;
    const int wid  = tid >> 6;
    const int wm   = wid >> 1;
    const int wn   = wid & 1;
    const int tileM = blockIdx.x * 128;
    const int tileN = blockIdx.y * 128;
    const int c     = blockIdx.z;

    f32x4 acc[4][4];
#pragma unroll
    for (int mi = 0; mi < 4; ++mi)
#pragma unroll
        for (int ni = 0; ni < 4; ++ni)
            acc[mi][ni] = (f32x4){0.f, 0.f, 0.f, 0.f};

    // staging: slice s (=wid*4+j) covers rows 8s..8s+7; lane l -> row l>>3,
    // physical chunk l&7; source global chunk = (l&7) ^ (l>>3)  (XOR swizzle)
    const int srow = lane >> 3;
    const int gchunk = ((lane & 7) ^ srow) * 8;   // element offset of 8-elem chunk

    const uint16_t* Ag = xb + (size_t)tileM * 1024;
    const uint16_t* Bg = Wb + ((size_t)c << 20) + (size_t)tileN * 1024;

    const int quad = lane >> 4;
    const int l15  = lane & 15;
    const int l7   = lane & 7;

    for (int kt = 0; kt < 16; ++kt) {
        const int k0 = kt * 64;
#pragma unroll
        for (int j = 0; j < 4; ++j) {
            const int s = wid * 4 + j;
            const uint16_t* ga = Ag + (size_t)(s * 8 + srow) * 1024 + k0 + gchunk;
            __builtin_amdgcn_global_load_lds(
                (const __attribute__((address_space(1))) void*)ga,
                (__attribute__((address_space(3))) void*)(As + s * 512), 16, 0, 0);
            const uint16_t* gb = Bg + (size_t)(s * 8 + srow) * 1024 + k0 + gchunk;
            __builtin_amdgcn_global_load_lds(
                (const __attribute__((address_space(1))) void*)gb,
                (__attribute__((address_space(3))) void*)(Bs + s * 512), 16, 0, 0);
        }
        __syncthreads();

#pragma unroll
        for (int ks = 0; ks < 2; ++ks) {
            bf16x8 af[4], bfr[4];
#pragma unroll
            for (int mi = 0; mi < 4; ++mi) {
                const int row = wm * 64 + mi * 16 + l15;
                const int ch  = (ks * 4 + quad) ^ l7;     // physical chunk
                af[mi] = *(const bf16x8*)(As + row * 64 + ch * 8);
            }
#pragma unroll
            for (int ni = 0; ni < 4; ++ni) {
                const int row = wn * 64 + ni * 16 + l15;
                const int ch  = (ks * 4 + quad) ^ l7;
                bfr[ni] = *(const bf16x8*)(Bs + row * 64 + ch * 8);
            }
#pragma unroll
            for (int mi = 0; mi < 4; ++mi)
#pragma unroll
                for (int ni = 0; ni < 4; ++ni)
                    acc[mi][ni] = __builtin_amdgcn_mfma_f32_16x16x32_bf16(
                        af[mi], bfr[ni], acc[mi][ni], 0, 0, 0);
        }
        __syncthreads();
    }

    // ---- Epilogue phase 1: acc + bias -> LDS tile (bf16, bank-swizzled) ----
    // C/D layout: col = lane&15, row = quad*4 + reg  [m89/m91 verified]
    // logical col = wn*64 + ni*16 + l15; phys 16-col group XORed with quad
    // ((row>>2)&3 == quad for all acc rows) -> one store inst spans 4 distinct
    // 8-bank groups = all 32 banks.
    float bv[4];
#pragma unroll
    for (int ni = 0; ni < 4; ++ni)
        bv[ni] = biases[c * OUT_DIM + tileN + wn * 64 + l15 + ni * 16];

#pragma unroll
    for (int mi = 0; mi < 4; ++mi) {
#pragma unroll
        for (int r = 0; r < 4; ++r) {
            const int row = wm * 64 + mi * 16 + quad * 4 + r;
            uint16_t* dst = smem + row * 128 + wn * 64 + l15;
#pragma unroll
            for (int ni = 0; ni < 4; ++ni)
                dst[((ni ^ quad) << 4)] = f2bf(acc[mi][ni][r] + bv[ni]);
        }
    }
    __syncthreads();

    // ---- Epilogue phase 2: contiguous b128 re-read -> coalesced P stores ----
    uint16_t* Pc = P + (size_t)c * ((size_t)BATCH * OUT_DIM);
#pragma unroll
    for (int p = 0; p < 8; ++p) {
        const int f     = p * 256 + tid;
        const int row   = f >> 4;            // 0..127
        const int chunk = f & 15;            // 8-elem chunk within row
        const int pch   = chunk ^ (((row >> 2) & 3) << 1);  // un-swizzle
        u16x8 v = *(const u16x8*)(smem + row * 128 + pch * 8);
        *(u16x8*)(Pc + (size_t)(tileM + row) * OUT_DIM + tileN + chunk * 8) = v;
    }
}

// ---------------------------------------------------------------------------
// reduce: out[m,n] = sum_c alpha[m,c] * P_c[m,n]   (bias already in P)
// 2 rows per block, 16B loads per slice.
// ---------------------------------------------------------------------------
__global__ __launch_bounds__(256) void reduce_k(
    const uint16_t* __restrict__ P, const float* __restrict__ alphaWS,
    float* __restrict__ out)
{
    const int m  = blockIdx.x * 2 + (threadIdx.x >> 7);
    const int ch = threadIdx.x & 127;        // 8-col chunk
    const size_t stride = (size_t)BATCH * OUT_DIM;
    const size_t base = (size_t)m * OUT_DIM + ch * 8;

    const float4 al = *(const float4*)(alphaWS + 4 * m);
    u16x8 p0 = *(const u16x8*)(P + 0 * stride + base);
    u16x8 p1 = *(const u16x8*)(P + 1 * stride + base);
    u16x8 p2 = *(const u16x8*)(P + 2 * stride + base);
    u16x8 p3 = *(const u16x8*)(P + 3 * stride + base);

    float r[8];
#pragma unroll
    for (int j = 0; j < 8; ++j)
        r[j] = al.x * bf2f(p0[j]) + al.y * bf2f(p1[j])
             + al.z * bf2f(p2[j]) + al.w * bf2f(p3[j]);

    float4 lo = {r[0], r[1], r[2], r[3]};
    float4 hi = {r[4], r[5], r[6], r[7]};
    ((float4*)(out + base))[0] = lo;
    ((float4*)(out + base))[1] = hi;
}

extern "C" void kernel_launch(void* const* d_in, const int* in_sizes, int n_in,
                              void* d_out, int out_size, void* d_ws, size_t ws_size,
                              hipStream_t stream)
{
    const float* x       = (const float*)d_in[0];  // (B, IN)
    const float* phase   = (const float*)d_in[1];  // (B,)
    const float* weights = (const float*)d_in[2];  // (4, OUT, IN)
    const float* biases  = (const float*)d_in[3];  // (4, OUT)
    const float* basis   = (const float*)d_in[4];  // (4, 4)
    float* out = (float*)d_out;                    // (B, OUT)

    // Workspace: xb bf16 8 MB | Wb bf16 8 MB | alpha 64 KB | P bf16 32 MB
    uint16_t* xb = (uint16_t*)d_ws;
    uint16_t* Wb = xb + (size_t)BATCH * IN_DIM;
    float* alphaWS = (float*)(Wb + (size_t)4 * OUT_DIM * IN_DIM);
    uint16_t* P = (uint16_t*)(alphaWS + (size_t)BATCH * 4);

    prep<<<2 * BATCH, 256, 0, stream>>>(x, phase, basis, weights, xb, Wb, alphaWS);

    dim3 grid(BATCH / 128, OUT_DIM / 128, 4);  // M fastest for XCD L2 locality
    gemm_split<<<grid, 256, 0, stream>>>(xb, Wb, biases, P);

    reduce_k<<<BATCH / 2, 256, 0, stream>>>(P, alphaWS, out);
}

// Round 6
// 128.667 us; speedup vs baseline: 1.0199x; 1.0199x over previous
//
#include <hip/hip_runtime.h>
#include <stdint.h>

// Problem constants (fixed by the reference)
#define BATCH   4096
#define IN_DIM  1024
#define OUT_DIM 1024

typedef __bf16 bf16x8 __attribute__((ext_vector_type(8)));
typedef float  f32x4  __attribute__((ext_vector_type(4)));

// fp32 -> bf16 bits, round-to-nearest-even
__device__ __forceinline__ uint16_t f2bf(float f) {
    union { float f; uint32_t u; } v; v.f = f;
    uint32_t u = v.u;
    uint32_t r = (u + 0x7FFFu + ((u >> 16) & 1u)) >> 16;
    return (uint16_t)r;
}

__device__ __forceinline__ float bf2f(uint16_t h) {
    union { uint32_t u; float f; } v; v.u = ((uint32_t)h) << 16;
    return v.f;
}

// ---------------------------------------------------------------------------
// prep: blocks 0..4095   -> convert x row b to bf16, compute alpha[b][0..3]
//       blocks 4096..8191 -> convert W (flat 4M floats) to bf16
// ---------------------------------------------------------------------------
__global__ __launch_bounds__(256) void prep(
    const float* __restrict__ x, const float* __restrict__ phase,
    const float* __restrict__ basis, const float* __restrict__ W,
    uint16_t* __restrict__ xb, uint16_t* __restrict__ Wb,
    float* __restrict__ alphaWS)
{
    const int bid = blockIdx.x;
    const int tid = threadIdx.x;

    if (bid < BATCH) {
        const int b = bid;
        const float HALF_PI = 1.5707963267948966f;
        float s  = phase[b] / HALF_PI;
        int   q  = (int)floorf(s);
        q = q < 0 ? 0 : (q > 3 ? 3 : q);
        float t  = s - (float)q;
        float t2 = t * t, t3 = t2 * t;

        float coef[4];
#pragma unroll
        for (int j = 0; j < 4; ++j)
            coef[j] = t3 * basis[j] + t2 * basis[4 + j] + t * basis[8 + j] + basis[12 + j];

        // CPI[q][k] = (q+k+3)%4  =>  alpha[c] = coef[(c - q + 1) & 3]
        if (tid < 4) alphaWS[b * 4 + tid] = coef[(tid - q + 1) & 3];

        float4 xv = ((const float4*)(x + (size_t)b * IN_DIM))[tid];
        ushort4 o;
        o.x = f2bf(xv.x); o.y = f2bf(xv.y); o.z = f2bf(xv.z); o.w = f2bf(xv.w);
        ((ushort4*)(xb + (size_t)b * IN_DIM))[tid] = o;
    } else {
        const int j = bid - BATCH;                 // 0..4095, W has 1M float4s
        float4 wv = ((const float4*)W)[j * 256 + tid];
        ushort4 o;
        o.x = f2bf(wv.x); o.y = f2bf(wv.y); o.z = f2bf(wv.z); o.w = f2bf(wv.w);
        ((ushort4*)Wb)[j * 256 + tid] = o;
    }
}

// ---------------------------------------------------------------------------
// gemm_split: P_c[m,n] = bf16( sum_k x[m,k] * W[c,n,k] )   (K = 1024 per c)
// 128x128 tile, BK=64, 256 threads (2x2 waves, each 64x64 via 4x4 MFMA).
// grid = (32 M-tiles, 8 N-tiles, 4 c) = 1024 blocks -> 4 blocks/CU.
// Partials stored bf16 (halves epilogue + reduce traffic vs fp32).
// LDS XOR swizzle: physical chunk = logical chunk ^ (row & 7), applied on the
// global source address (global_load_lds dest is lane-contiguous, no padding).
// Epilogue: plain scalar stores — R5's LDS-repack epilogue measured +2.5 us
// (extra barrier + LDS round-trip; scalar stores overlap other blocks' MFMA
// at 4 blocks/CU). Keep it simple.
// ---------------------------------------------------------------------------
__global__ __launch_bounds__(256, 4) void gemm_split(
    const uint16_t* __restrict__ xb, const uint16_t* __restrict__ Wb,
    uint16_t* __restrict__ P)
{
    __shared__ uint16_t As[128 * 64];
    __shared__ uint16_t Bs[128 * 64];

    const int tid  = threadIdx.x;
    const int lane = tid & 63;
    const int wid  = tid >> 6;
    const int wm   = wid >> 1;
    const int wn   = wid & 1;
    const int tileM = blockIdx.x * 128;
    const int tileN = blockIdx.y * 128;
    const int c     = blockIdx.z;

    f32x4 acc[4][4];
#pragma unroll
    for (int mi = 0; mi < 4; ++mi)
#pragma unroll
        for (int ni = 0; ni < 4; ++ni)
            acc[mi][ni] = (f32x4){0.f, 0.f, 0.f, 0.f};

    // staging: slice s (=wid*4+j) covers rows 8s..8s+7; lane l -> row l>>3,
    // physical chunk l&7; source global chunk = (l&7) ^ (l>>3)  (XOR swizzle)
    const int srow = lane >> 3;
    const int gchunk = ((lane & 7) ^ srow) * 8;   // element offset of 8-elem chunk

    const uint16_t* Ag = xb + (size_t)tileM * 1024;
    const uint16_t* Bg = Wb + ((size_t)c << 20) + (size_t)tileN * 1024;

    const int quad = lane >> 4;
    const int l7   = lane & 7;

    for (int kt = 0; kt < 16; ++kt) {
        const int k0 = kt * 64;
#pragma unroll
        for (int j = 0; j < 4; ++j) {
            const int s = wid * 4 + j;
            const uint16_t* ga = Ag + (size_t)(s * 8 + srow) * 1024 + k0 + gchunk;
            __builtin_amdgcn_global_load_lds(
                (const __attribute__((address_space(1))) void*)ga,
                (__attribute__((address_space(3))) void*)(As + s * 512), 16, 0, 0);
            const uint16_t* gb = Bg + (size_t)(s * 8 + srow) * 1024 + k0 + gchunk;
            __builtin_amdgcn_global_load_lds(
                (const __attribute__((address_space(1))) void*)gb,
                (__attribute__((address_space(3))) void*)(Bs + s * 512), 16, 0, 0);
        }
        __syncthreads();

#pragma unroll
        for (int ks = 0; ks < 2; ++ks) {
            bf16x8 af[4], bfr[4];
#pragma unroll
            for (int mi = 0; mi < 4; ++mi) {
                const int row = wm * 64 + mi * 16 + (lane & 15);
                const int ch  = (ks * 4 + quad) ^ l7;     // physical chunk
                af[mi] = *(const bf16x8*)(As + row * 64 + ch * 8);
            }
#pragma unroll
            for (int ni = 0; ni < 4; ++ni) {
                const int row = wn * 64 + ni * 16 + (lane & 15);
                const int ch  = (ks * 4 + quad) ^ l7;
                bfr[ni] = *(const bf16x8*)(Bs + row * 64 + ch * 8);
            }
#pragma unroll
            for (int mi = 0; mi < 4; ++mi)
#pragma unroll
                for (int ni = 0; ni < 4; ++ni)
                    acc[mi][ni] = __builtin_amdgcn_mfma_f32_16x16x32_bf16(
                        af[mi], bfr[ni], acc[mi][ni], 0, 0, 0);
        }
        __syncthreads();
    }

    // partial store, bf16 (alpha/bias applied in reduce, fp32)
    // C/D layout: col = lane&15, row = quad*4 + reg  [m89/m91 verified]
    uint16_t* Pc = P + (size_t)c * (BATCH * (size_t)OUT_DIM);
    const int col0 = tileN + wn * 64 + (lane & 15);
#pragma unroll
    for (int mi = 0; mi < 4; ++mi) {
#pragma unroll
        for (int r = 0; r < 4; ++r) {
            const int m = tileM + wm * 64 + mi * 16 + quad * 4 + r;
#pragma unroll
            for (int ni = 0; ni < 4; ++ni)
                Pc[(size_t)m * OUT_DIM + col0 + ni * 16] = f2bf(acc[mi][ni][r]);
        }
    }
}

// ---------------------------------------------------------------------------
// reduce: out[m,n] = sum_c alpha[m,c] * (P_c[m,n] + bias[c,n])
// One block per row m; thread t handles 4 consecutive cols.
// ---------------------------------------------------------------------------
__global__ __launch_bounds__(256) void reduce_k(
    const uint16_t* __restrict__ P, const float* __restrict__ alphaWS,
    const float* __restrict__ biases, float* __restrict__ out)
{
    const int m = blockIdx.x;
    const int t = threadIdx.x;
    const size_t stride = (size_t)BATCH * OUT_DIM;

    const float4 al = *(const float4*)(alphaWS + 4 * m);
    float4 r = {0.f, 0.f, 0.f, 0.f};
    const float a[4] = {al.x, al.y, al.z, al.w};
#pragma unroll
    for (int c = 0; c < 4; ++c) {
        ushort4 p = ((const ushort4*)(P + c * stride + (size_t)m * OUT_DIM))[t];
        float4 b  = ((const float4*)(biases + c * OUT_DIM))[t];
        r.x += a[c] * (bf2f(p.x) + b.x);
        r.y += a[c] * (bf2f(p.y) + b.y);
        r.z += a[c] * (bf2f(p.z) + b.z);
        r.w += a[c] * (bf2f(p.w) + b.w);
    }
    ((float4*)(out + (size_t)m * OUT_DIM))[t] = r;
}

extern "C" void kernel_launch(void* const* d_in, const int* in_sizes, int n_in,
                              void* d_out, int out_size, void* d_ws, size_t ws_size,
                              hipStream_t stream)
{
    const float* x       = (const float*)d_in[0];  // (B, IN)
    const float* phase   = (const float*)d_in[1];  // (B,)
    const float* weights = (const float*)d_in[2];  // (4, OUT, IN)
    const float* biases  = (const float*)d_in[3];  // (4, OUT)
    const float* basis   = (const float*)d_in[4];  // (4, 4)
    float* out = (float*)d_out;                    // (B, OUT)

    // Workspace: xb bf16 8 MB | Wb bf16 8 MB | alpha 64 KB | P bf16 32 MB
    uint16_t* xb = (uint16_t*)d_ws;
    uint16_t* Wb = xb + (size_t)BATCH * IN_DIM;
    float* alphaWS = (float*)(Wb + (size_t)4 * OUT_DIM * IN_DIM);
    uint16_t* P = (uint16_t*)(alphaWS + (size_t)BATCH * 4);

    prep<<<2 * BATCH, 256, 0, stream>>>(x, phase, basis, weights, xb, Wb, alphaWS);

    dim3 grid(BATCH / 128, OUT_DIM / 128, 4);  // M fastest for XCD L2 locality
    gemm_split<<<grid, 256, 0, stream>>>(xb, Wb, P);

    reduce_k<<<BATCH, 256, 0, stream>>>(P, alphaWS, biases, out);
}